// Round 18
// baseline (208.027 us; speedup 1.0000x reference)
//
#include <hip/hip_runtime.h>

// DISCO S2 conv, equiangular 360x720 -> 180x360, K=3, B*C=128.
// out[bc, k*180+t, p] = sum_{e in seg(k,t)} val[e]*qw[lat[e]] * x[bc, lat[e], (lon[e]-2p-2) mod 720]
//
// Round-18: PB=6 — one wave covers all 360 p (60 lanes x 6).
//  - halves wave-visits per entry (2 -> 1): half the ds_read instructions,
//    half the header decodes / address setup. FMA count unchanged.
//  - LDS split into L(ch01)/H(ch23) 8-B slot planes (25.6 KB total) so the
//    lane stride stays 12 dwords (benign bank pattern), not 24.
//  - window depth 7 per parity, period-7 rotation, 14-entry unrolled body.
//  - rows -> pairs by parity (R14); runs within a row split between the
//    pair's two waves (each wave reads only its own headers).
//  - 4-wave accumulator combine via LDS overlay in epilogue.
//  - staging (T14 issue-early/write-late), prep kernels, grid = R14.

#define NLAT_IN  360
#define NLON_IN  720
#define NLAT_OUT 180
#define NLON_OUT 360
#define KSIZE    3
#define NSEG     (KSIZE * NLAT_OUT)    // 540
#define CHW      (NLAT_IN * NLON_IN)   // 259200
#define BCTOT    128
#define G        4
#define NBCG     (BCTOT / G)           // 32
#define MAXR     2
#define PH       10
#define NTHREADS 256
#define SLOTS    400                   // 360 + 40 wrap mirror (max reach qA+37)
#define ROWB     (SLOTS * 8)           // 3200 B per plane (8-B slots)
#define NPLANES  (MAXR * 2)            // 4
#define LHOFFV   (NPLANES * SLOTS)     // v2f offset of H block
#define LHOFF    (LHOFFV * 8)          // byte offset of H block (12800)
#define MIRROR   (SLOTS - NLON_OUT)    // 40

typedef float v2f __attribute__((ext_vector_type(2)));

__device__ __forceinline__ void PKF(v2f& a, v2f x, v2f c) {
    asm("v_pk_fma_f32 %0, %1, %2, %0" : "+v"(a) : "v"(x), "v"(c));
}

// ---------------- prep ----------------

__global__ void prep1_kernel(const int* __restrict__ seg, const int* __restrict__ lat,
                             const float* __restrict__ val, int nnz,
                             int* __restrict__ ptrh, int* __restrict__ hbase,
                             int* __restrict__ hlast, int* __restrict__ flags) {
    int idx = blockIdx.x * blockDim.x + threadIdx.x;
    if (idx >= NSEG * PH) return;
    int s = idx / PH, j = idx - s * PH;
    int lo = 0, hi = nnz;
    while (lo < hi) { int m = (lo + hi) >> 1; if (seg[m] < s) lo = m + 1; else hi = m; }
    int e0 = lo;
    lo = e0; hi = nnz;
    while (lo < hi) { int m = (lo + hi) >> 1; if (seg[m] < s + 1) lo = m + 1; else hi = m; }
    int e1 = lo;
    if (e0 >= e1) {
        ptrh[idx] = e0; flags[idx] = 0;
        if (j == 0) { hbase[s] = 1 << 28; hlast[s] = -(1 << 28); }
        return;
    }
    int hb = lat[e0];
    if (j == 0) { hbase[s] = hb; hlast[s] = lat[e1 - 1]; }
    int a;
    { int tg = hb + j; lo = e0; hi = e1;
      while (lo < hi) { int m = (lo + hi) >> 1; if (lat[m] < tg) lo = m + 1; else hi = m; }
      a = lo; }
    ptrh[idx] = a;
    int f = 0;
    if (j < PH - 1) {
        int tg = hb + j + 1; lo = a; hi = e1;
        while (lo < hi) { int m = (lo + hi) >> 1; if (lat[m] < tg) lo = m + 1; else hi = m; }
        int b = lo;
        if (b - a == NLON_IN) {
            float v0 = val[a], v1 = val[a + 240], v2 = val[a + 480];
            float d = fmaxf(fabsf(v0 - v1), fmaxf(fabsf(v0 - v2), fabsf(v1 - v2)));
            f = (d < 1e-5f) ? 1 : 0;
        }
    }
    flags[idx] = f;
}

__global__ void cf_kernel(const int* __restrict__ lat, const float* __restrict__ val,
                          const float* __restrict__ qw, int nnz, float* __restrict__ cfb) {
    int e = blockIdx.x * blockDim.x + threadIdx.x;
    if (e < nnz) cfb[e] = val[e] * qw[lat[e]];
}

// wave-parallel run builder: one wave per (s,j) row; 64-entry chunks.
__global__ void runs_kernel(const int* __restrict__ lon, const int* __restrict__ ptrh,
                            const int* __restrict__ flags,
                            int* __restrict__ runcnt, uint2* __restrict__ runslab) {
    const int idx  = blockIdx.x * 4 + (threadIdx.x >> 6);
    if (idx >= NSEG * PH) return;
    const int lane = threadIdx.x & 63;
    const int j = idx % PH;
    int runbase = 0;
    if (j < PH - 1) {
        const int a = ptrh[idx], b = ptrh[idx + 1];
        if (b > a && !flags[idx]) {
            for (int c = a; c < b; c += 64) {
                const int e = c + lane;
                const bool active = e < b;
                const int w   = active ? lon[e] : 0;
                const int wm1 = (active && e > a) ? lon[e - 1] : -99;
                const bool isStart = active && (lane == 0 || w != wm1 + 1);
                const unsigned long long mask = __ballot(isStart);
                if (isStart) {
                    const int cnt = min(64, b - c);
                    unsigned long long hv = (mask >> lane) >> 1;
                    const int len = hv ? __ffsll((long long)hv) : (cnt - lane);
                    const int cidx = __popcll(mask & ((1ull << lane) - 1ull));
                    const int s0 = ((w >> 1) + NLON_OUT - 1) % NLON_OUT;
                    runslab[a + runbase + cidx] = make_uint2(
                        (unsigned)e, (unsigned)(s0 | ((w & 1) << 9) | (len << 11)));
                }
                runbase += __popcll(mask);
            }
        }
    }
    if (lane == 0) runcnt[idx] = runbase;
}

// ---------------- main ----------------

__global__ __launch_bounds__(NTHREADS) void disco_kernel(
    const float* __restrict__ x,
    const float* __restrict__ cfb,
    const uint2* __restrict__ runslab,
    const int*   __restrict__ runcnt,
    const int*   __restrict__ ptrh,
    const int*   __restrict__ hbase,
    const int*   __restrict__ hlast,
    const int*   __restrict__ flags,
    float*       __restrict__ out)
{
    __shared__ v2f smem[2 * NPLANES * SLOTS];  // 25,600 B: L planes then H planes
    v2f (*accbuf)[12] = (v2f(*)[12])smem;      // epilogue overlay [3*64][12] = 18,432 B

#define LDS_L(pl, m) smem[(pl) * SLOTS + (m)]
#define LDS_H(pl, m) smem[LHOFFV + (pl) * SLOTS + (m)]

    const int tid  = threadIdx.x;
    const int lane = tid & 63;
    const int wid  = tid >> 6;                 // 0..3
    const int pair = wid >> 1;                 // 0,1 : row-parity owner
    const int wsub = wid & 1;                  // run-parity within pair
    int lp = 59 - lane; if (lp < 0) lp = 0;    // reversed lane -> ascending slots
    const int p0   = 6 * lp;
    const int bc0  = blockIdx.x * G;
    const int ty   = blockIdx.y;
    const int t    = (ty & 1) ? (NLAT_OUT - 1 - (ty >> 1)) : (ty >> 1); // poles first
    const int s    = blockIdx.z * NLAT_OUT + t;
    const int hb = hbase[s], hl = hlast[s];    // empty: hb > hl

    // acc[j] covers p = p0+j, 4 channels as (l=ch01, h=ch23)
    v2f a0l = {0.f,0.f}, a0h = a0l, a1l = a0l, a1h = a0l, a2l = a0l, a2h = a0l;
    v2f a3l = a0l, a3h = a0l, a4l = a0l, a4h = a0l, a5l = a0l, a5h = a0l;
    const char* lb = (const char*)smem;

    float2 sv0[4], sv1[4], sv2[4];             // T14 staging registers
    const float* xb = x + (size_t)bc0 * CHW;

#define LOADW(R0)                                                              \
    {                                                                          \
        {   const int idx_ = tid;                                              \
            const int rr_ = idx_ >= 360;                                       \
            const int m_  = idx_ - 360 * rr_;                                  \
            const int row_ = min((R0) + rr_, hl);                              \
            const float* xr_ = xb + (size_t)row_ * NLON_IN + 2 * m_;           \
            sv0[0] = *(const float2*)(xr_);                                    \
            sv0[1] = *(const float2*)(xr_ + CHW);                              \
            sv0[2] = *(const float2*)(xr_ + 2 * CHW);                          \
            sv0[3] = *(const float2*)(xr_ + 3 * CHW);                          \
        }                                                                      \
        {   const int idx_ = tid + 256;                                        \
            const int rr_ = idx_ >= 360;                                       \
            const int m_  = idx_ - 360 * rr_;                                  \
            const int row_ = min((R0) + rr_, hl);                              \
            const float* xr_ = xb + (size_t)row_ * NLON_IN + 2 * m_;           \
            sv1[0] = *(const float2*)(xr_);                                    \
            sv1[1] = *(const float2*)(xr_ + CHW);                              \
            sv1[2] = *(const float2*)(xr_ + 2 * CHW);                          \
            sv1[3] = *(const float2*)(xr_ + 3 * CHW);                          \
        }                                                                      \
        if (tid < 208) {                                                       \
            const int m_  = tid + 512 - 360;                                   \
            const int row_ = min((R0) + 1, hl);                                \
            const float* xr_ = xb + (size_t)row_ * NLON_IN + 2 * m_;           \
            sv2[0] = *(const float2*)(xr_);                                    \
            sv2[1] = *(const float2*)(xr_ + CHW);                              \
            sv2[2] = *(const float2*)(xr_ + 2 * CHW);                          \
            sv2[3] = *(const float2*)(xr_ + 3 * CHW);                          \
        }                                                                      \
    }

#define WR1(SV, RR, M)                                                         \
    {                                                                          \
        LDS_L(2*(RR)+0, (M)) = (v2f){SV[0].x, SV[1].x};                        \
        LDS_H(2*(RR)+0, (M)) = (v2f){SV[2].x, SV[3].x};                        \
        LDS_L(2*(RR)+1, (M)) = (v2f){SV[0].y, SV[1].y};                        \
        LDS_H(2*(RR)+1, (M)) = (v2f){SV[2].y, SV[3].y};                        \
        if ((M) < MIRROR) {                                                    \
            LDS_L(2*(RR)+0, NLON_OUT+(M)) = (v2f){SV[0].x, SV[1].x};           \
            LDS_H(2*(RR)+0, NLON_OUT+(M)) = (v2f){SV[2].x, SV[3].x};           \
            LDS_L(2*(RR)+1, NLON_OUT+(M)) = (v2f){SV[0].y, SV[1].y};           \
            LDS_H(2*(RR)+1, NLON_OUT+(M)) = (v2f){SV[2].y, SV[3].y};           \
        }                                                                      \
    }

#define WRITEW()                                                               \
    {                                                                          \
        { const int idx_ = tid;       const int rr_ = idx_ >= 360;             \
          const int m_ = idx_ - 360 * rr_; WR1(sv0, rr_, m_); }                \
        { const int idx_ = tid + 256; const int rr_ = idx_ >= 360;             \
          const int m_ = idx_ - 360 * rr_; WR1(sv1, rr_, m_); }                \
        if (tid < 208) { const int m_ = tid + 512 - 360; WR1(sv2, 1, m_); }    \
    }

// A-parity entry: load new slot into LD, consume S0..S5 (slots m..m+5 -> acc5..acc0)
#define AE(LD, S0,S1,S2,S3,S4,S5, CS)                                          \
    LD##l = *(const v2f*)(ldA); LD##h = *(const v2f*)(ldA + LHOFF); ldA += 8;  \
    { const float cs_ = (CS); const v2f c_ = (v2f){cs_, cs_};                  \
      PKF(a5l, S0##l, c_); PKF(a5h, S0##h, c_);                                \
      PKF(a4l, S1##l, c_); PKF(a4h, S1##h, c_);                                \
      PKF(a3l, S2##l, c_); PKF(a3h, S2##h, c_);                                \
      PKF(a2l, S3##l, c_); PKF(a2h, S3##h, c_);                                \
      PKF(a1l, S4##l, c_); PKF(a1h, S4##h, c_);                                \
      PKF(a0l, S5##l, c_); PKF(a0h, S5##h, c_); }

#define BE(LD, S0,S1,S2,S3,S4,S5, CS)                                          \
    LD##l = *(const v2f*)(ldB); LD##h = *(const v2f*)(ldB + LHOFF); ldB += 8;  \
    { const float cs_ = (CS); const v2f c_ = (v2f){cs_, cs_};                  \
      PKF(a5l, S0##l, c_); PKF(a5h, S0##h, c_);                                \
      PKF(a4l, S1##l, c_); PKF(a4h, S1##h, c_);                                \
      PKF(a3l, S2##l, c_); PKF(a3h, S2##h, c_);                                \
      PKF(a2l, S3##l, c_); PKF(a2h, S3##h, c_);                                \
      PKF(a1l, S4##l, c_); PKF(a1h, S4##h, c_);                                \
      PKF(a0l, S5##l, c_); PKF(a0h, S5##h, c_); }

    if (hb <= hl) {
        LOADW(hb);                              // prologue: first window in flight
        for (int r0 = hb; r0 <= hl; r0 += MAXR) {
            const int rn = min(MAXR, hl - r0 + 1);
            __syncthreads();                    // readers of previous window done
            WRITEW();                           // vmcnt wait hidden under prev compute
            if (r0 + MAXR <= hl) LOADW(r0 + MAXR);
            __syncthreads();                    // LDS ready
            // ---- compute window ----
            for (int r = 0; r < rn; ++r) {
                const int j = (r0 + r) - hb;
                if (j < 0 || j >= PH - 1) continue;
                if ((j & 1) != pair) continue;   // wave-uniform pair gate
                const int idx = s * PH + j;
                const int a = ptrh[idx], b = ptrh[idx + 1];
                if (a >= b) continue;
                const int rp0 = (j & 1) * 2;
                if (flags[idx]) {                // constant-val full row: cf*rowsum
                    if (wsub == 0) {             // one wave of the pair only
                        v2f vl = {0.f, 0.f}, vh = vl;
                        for (int m = lane; m < NLON_OUT; m += 64) {
                            vl += LDS_L(rp0, m) + LDS_L(rp0 + 1, m);
                            vh += LDS_H(rp0, m) + LDS_H(rp0 + 1, m);
                        }
#pragma unroll
                        for (int o = 32; o >= 1; o >>= 1) {
                            vl.x += __shfl_xor(vl.x, o); vl.y += __shfl_xor(vl.y, o);
                            vh.x += __shfl_xor(vh.x, o); vh.y += __shfl_xor(vh.y, o);
                        }
                        const float cf = cfb[a];
                        const v2f c = (v2f){cf, cf};
                        PKF(a0l, vl, c); PKF(a0h, vh, c);
                        PKF(a1l, vl, c); PKF(a1h, vh, c);
                        PKF(a2l, vl, c); PKF(a2h, vh, c);
                        PKF(a3l, vl, c); PKF(a3h, vh, c);
                        PKF(a4l, vl, c); PKF(a4h, vh, c);
                        PKF(a5l, vl, c); PKF(a5h, vh, c);
                    }
                    continue;
                }
                const int rc = runcnt[idx];
                for (int rr = wsub; rr < rc; rr += 2) {   // run split across pair's waves
                    const uint2 R = runslab[a + rr];
                    const int e0  = __builtin_amdgcn_readfirstlane((int)R.x);
                    const int y   = __builtin_amdgcn_readfirstlane((int)R.y);
                    const int s0A = y & 511;
                    const int odd = (y >> 9) & 1;
                    const int len = y >> 11;
                    int qA = s0A - p0 - 5; qA += (qA >> 31) & NLON_OUT;   // [0,359]
                    const char* baseA = lb + (size_t)(rp0 + odd) * ROWB + ((size_t)qA << 3);
                    const char* baseB = lb + (size_t)(rp0 + (odd ^ 1)) * ROWB
                                           + ((size_t)(qA + odd) << 3);
                    const float* cfp = cfb + e0;
                    int i = 0;
                    if (len >= 14) {
                        const char* ldA = baseA;
                        const char* ldB = baseB;
                        v2f w0l = *(const v2f*)(ldA +  0), w0h = *(const v2f*)(ldA + LHOFF +  0);
                        v2f w1l = *(const v2f*)(ldA +  8), w1h = *(const v2f*)(ldA + LHOFF +  8);
                        v2f w2l = *(const v2f*)(ldA + 16), w2h = *(const v2f*)(ldA + LHOFF + 16);
                        v2f w3l = *(const v2f*)(ldA + 24), w3h = *(const v2f*)(ldA + LHOFF + 24);
                        v2f w4l = *(const v2f*)(ldA + 32), w4h = *(const v2f*)(ldA + LHOFF + 32);
                        v2f w5l = *(const v2f*)(ldA + 40), w5h = *(const v2f*)(ldA + LHOFF + 40);
                        v2f u0l = *(const v2f*)(ldB +  0), u0h = *(const v2f*)(ldB + LHOFF +  0);
                        v2f u1l = *(const v2f*)(ldB +  8), u1h = *(const v2f*)(ldB + LHOFF +  8);
                        v2f u2l = *(const v2f*)(ldB + 16), u2h = *(const v2f*)(ldB + LHOFF + 16);
                        v2f u3l = *(const v2f*)(ldB + 24), u3h = *(const v2f*)(ldB + LHOFF + 24);
                        v2f u4l = *(const v2f*)(ldB + 32), u4h = *(const v2f*)(ldB + LHOFF + 32);
                        v2f u5l = *(const v2f*)(ldB + 40), u5h = *(const v2f*)(ldB + LHOFF + 40);
                        v2f w6l, w6h, u6l, u6h;
                        ldA += 48; ldB += 48;
                        for (; i + 14 <= len; i += 14) {
                            AE(w6, w0,w1,w2,w3,w4,w5, cfp[i +  0]);
                            BE(u6, u0,u1,u2,u3,u4,u5, cfp[i +  1]);
                            AE(w0, w1,w2,w3,w4,w5,w6, cfp[i +  2]);
                            BE(u0, u1,u2,u3,u4,u5,u6, cfp[i +  3]);
                            AE(w1, w2,w3,w4,w5,w6,w0, cfp[i +  4]);
                            BE(u1, u2,u3,u4,u5,u6,u0, cfp[i +  5]);
                            AE(w2, w3,w4,w5,w6,w0,w1, cfp[i +  6]);
                            BE(u2, u3,u4,u5,u6,u0,u1, cfp[i +  7]);
                            AE(w3, w4,w5,w6,w0,w1,w2, cfp[i +  8]);
                            BE(u3, u4,u5,u6,u0,u1,u2, cfp[i +  9]);
                            AE(w4, w5,w6,w0,w1,w2,w3, cfp[i + 10]);
                            BE(u4, u5,u6,u0,u1,u2,u3, cfp[i + 11]);
                            AE(w5, w6,w0,w1,w2,w3,w4, cfp[i + 12]);
                            BE(u5, u6,u0,u1,u2,u3,u4, cfp[i + 13]);
                        }
                    }
                    for (; i < len; ++i) {       // tail / short runs: direct reads
                        const int m_ = i >> 1;
                        const char* bp = ((i & 1) ? baseB : baseA) + ((size_t)m_ << 3);
                        const float cs_ = cfp[i]; const v2f c_ = (v2f){cs_, cs_};
                        const v2f s0l = *(const v2f*)(bp +  0), s0h = *(const v2f*)(bp + LHOFF +  0);
                        const v2f s1l = *(const v2f*)(bp +  8), s1h = *(const v2f*)(bp + LHOFF +  8);
                        const v2f s2l = *(const v2f*)(bp + 16), s2h = *(const v2f*)(bp + LHOFF + 16);
                        const v2f s3l = *(const v2f*)(bp + 24), s3h = *(const v2f*)(bp + LHOFF + 24);
                        const v2f s4l = *(const v2f*)(bp + 32), s4h = *(const v2f*)(bp + LHOFF + 32);
                        const v2f s5l = *(const v2f*)(bp + 40), s5h = *(const v2f*)(bp + LHOFF + 40);
                        PKF(a5l, s0l, c_); PKF(a5h, s0h, c_);
                        PKF(a4l, s1l, c_); PKF(a4h, s1h, c_);
                        PKF(a3l, s2l, c_); PKF(a3h, s2h, c_);
                        PKF(a2l, s3l, c_); PKF(a2h, s3h, c_);
                        PKF(a1l, s4l, c_); PKF(a1h, s4h, c_);
                        PKF(a0l, s5l, c_); PKF(a0h, s5h, c_);
                    }
                }
            }
        }
    }

    // ---- combine waves 1..3 into wave 0, store (accbuf overlays smem) ----
    __syncthreads();
    if (wid != 0) {
        v2f* d = accbuf[(wid - 1) * 64 + lane];
        d[0] = a0l; d[1]  = a0h; d[2]  = a1l; d[3]  = a1h;
        d[4] = a2l; d[5]  = a2h; d[6]  = a3l; d[7]  = a3h;
        d[8] = a4l; d[9]  = a4h; d[10] = a5l; d[11] = a5h;
    }
    __syncthreads();
    if (wid == 0 && lane < 60) {
#pragma unroll
        for (int wv = 0; wv < 3; ++wv) {
            const v2f* d = accbuf[wv * 64 + lane];
            a0l += d[0]; a0h += d[1];  a1l += d[2];  a1h += d[3];
            a2l += d[4]; a2h += d[5];  a3l += d[6];  a3h += d[7];
            a4l += d[8]; a4h += d[9];  a5l += d[10]; a5h += d[11];
        }
        const size_t cs_ = (size_t)NSEG * NLON_OUT;
        const size_t ob  = ((size_t)bc0 * NSEG + s) * NLON_OUT + p0;
        out[ob + 0]           = a0l.x; out[ob + 1]           = a1l.x;
        out[ob + 2]           = a2l.x; out[ob + 3]           = a3l.x;
        out[ob + 4]           = a4l.x; out[ob + 5]           = a5l.x;
        out[ob + cs_ + 0]     = a0l.y; out[ob + cs_ + 1]     = a1l.y;
        out[ob + cs_ + 2]     = a2l.y; out[ob + cs_ + 3]     = a3l.y;
        out[ob + cs_ + 4]     = a4l.y; out[ob + cs_ + 5]     = a5l.y;
        out[ob + 2*cs_ + 0]   = a0h.x; out[ob + 2*cs_ + 1]   = a1h.x;
        out[ob + 2*cs_ + 2]   = a2h.x; out[ob + 2*cs_ + 3]   = a3h.x;
        out[ob + 2*cs_ + 4]   = a4h.x; out[ob + 2*cs_ + 5]   = a5h.x;
        out[ob + 3*cs_ + 0]   = a0h.y; out[ob + 3*cs_ + 1]   = a1h.y;
        out[ob + 3*cs_ + 2]   = a2h.y; out[ob + 3*cs_ + 3]   = a3h.y;
        out[ob + 3*cs_ + 4]   = a4h.y; out[ob + 3*cs_ + 5]   = a5h.y;
    }
#undef LOADW
#undef WRITEW
#undef WR1
#undef AE
#undef BE
#undef LDS_L
#undef LDS_H
}

// ---------------- fallback (tiny ws) ----------------

__global__ void segptr_kernel(const int* __restrict__ seg, int nnz, int* __restrict__ ptr) {
    int s = blockIdx.x * blockDim.x + threadIdx.x;
    if (s > NSEG) return;
    if (s == NSEG) { ptr[NSEG] = nnz; return; }
    int lo = 0, hi = nnz;
    while (lo < hi) { int m = (lo + hi) >> 1; if (seg[m] < s) lo = m + 1; else hi = m; }
    ptr[s] = lo;
}

__global__ __launch_bounds__(384) void disco_simple_kernel(
    const float* __restrict__ x, const float* __restrict__ qw,
    const int* __restrict__ lat, const int* __restrict__ lon,
    const float* __restrict__ val, const int* __restrict__ ptr,
    float* __restrict__ out)
{
    const int p = threadIdx.x;
    if (p >= NLON_OUT) return;
    const int kt = blockIdx.x, bc0 = blockIdx.y * 8;
    const int e0 = ptr[kt], e1 = ptr[kt + 1];
    float acc[8];
#pragma unroll
    for (int g = 0; g < 8; ++g) acc[g] = 0.0f;
    const int pw = 2 * p + 2;
    const float* xb = x + (size_t)bc0 * CHW;
    for (int e = e0; e < e1; ++e) {
        const int h = lat[e], w = lon[e];
        const float cf = val[e] * qw[h];
        int col = w - pw; if (col < 0) col += NLON_IN;
        const float* src = xb + h * NLON_IN + col;
#pragma unroll
        for (int g = 0; g < 8; ++g) acc[g] = fmaf(cf, src[(size_t)g * CHW], acc[g]);
    }
    const size_t ob = ((size_t)bc0 * NSEG + kt) * NLON_OUT + p;
#pragma unroll
    for (int g = 0; g < 8; ++g) out[ob + (size_t)g * NSEG * NLON_OUT] = acc[g];
}

// ---------------- launcher ----------------

extern "C" void kernel_launch(void* const* d_in, const int* in_sizes, int n_in,
                              void* d_out, int out_size, void* d_ws, size_t ws_size,
                              hipStream_t stream)
{
    const float* x   = (const float*)d_in[0];   // [2,64,360,720] f32
    const float* qw  = (const float*)d_in[1];   // [360,1] f32
    const int*   seg = (const int*)  d_in[2];   // [nnz] i32 sorted asc
    const int*   lat = (const int*)  d_in[3];
    const int*   lon = (const int*)  d_in[4];
    const float* val = (const float*)d_in[5];
    const int    nnz = in_sizes[2];
    const int    nnzpad = (nnz + 3) & ~3;

    char* w = (char*)d_ws;
    size_t off = 0;
    int* ptrh   = (int*)(w + off); off += (size_t)NSEG * PH * 4;   // 21600
    int* hbase  = (int*)(w + off); off += NSEG * 4;
    int* hlast  = (int*)(w + off); off += NSEG * 4;
    int* flags  = (int*)(w + off); off += (size_t)NSEG * PH * 4;
    int* runcnt = (int*)(w + off); off += (size_t)NSEG * PH * 4;
    float* cfb  = (float*)(w + off); off += (size_t)nnzpad * 4;
    off = (off + 7) & ~(size_t)7;
    uint2* runslab = (uint2*)(w + off); off += (size_t)nnz * 8;

    if (ws_size < off) {                         // tiny ws: slow-but-correct path
        int* ptr = (int*)d_ws;
        segptr_kernel<<<(NSEG + 1 + 255) / 256, 256, 0, stream>>>(seg, nnz, ptr);
        dim3 grid(NSEG, BCTOT / 8);
        disco_simple_kernel<<<grid, 384, 0, stream>>>(x, qw, lat, lon, val, ptr,
                                                      (float*)d_out);
        return;
    }

    prep1_kernel<<<(NSEG * PH + 255) / 256, 256, 0, stream>>>(seg, lat, val, nnz,
                                                              ptrh, hbase, hlast, flags);
    cf_kernel<<<(nnz + 255) / 256, 256, 0, stream>>>(lat, val, qw, nnz, cfb);
    runs_kernel<<<(NSEG * PH + 3) / 4, 256, 0, stream>>>(lon, ptrh, flags,
                                                         runcnt, runslab);

    dim3 grid(NBCG, NLAT_OUT, KSIZE);
    disco_kernel<<<grid, NTHREADS, 0, stream>>>(x, cfb, runslab, runcnt,
                                                ptrh, hbase, hlast, flags,
                                                (float*)d_out);
}

// Round 19
// 152.116 us; speedup vs baseline: 1.3676x; 1.3676x over previous
//
#include <hip/hip_runtime.h>

// DISCO S2 conv, equiangular 360x720 -> 180x360, K=3, B*C=128.
// out[bc, k*180+t, p] = sum_{e in seg(k,t)} val[e]*qw[lat[e]] * x[bc, lat[e], (lon[e]-2p-2) mod 720]
//
// FINAL (= round-17, best measured: 152.0 us, absmax 3.8e-6).
// Structure: (bcg, t, k) k-split grid, poles-first dispatch; per block a
// sliding 2-row LDS window (parity-split float4 slots + 40-slot wrap mirror,
// 25.6 KB with epilogue accbuf overlay); T14 async staging (issue global->reg
// early, vmcnt+ds_write late); entries compressed into w-contiguous runs
// (wave-parallel ballot builder); hot loop = PB=3 sliding register window,
// v_pk_fma_f32, run-header prefetch; constant-val full rows (poles) collapse
// to a wave rowsum. R12/R13/R15/R16/R18 variants all regressed (see journal);
// this decomposition's practical floor is ~152 us with VALU 31%, HBM 22%,
// occupancy 41% - no single pipe saturated, all structural levers falsified.

#define NLAT_IN  360
#define NLON_IN  720
#define NLAT_OUT 180
#define NLON_OUT 360
#define KSIZE    3
#define NSEG     (KSIZE * NLAT_OUT)    // 540
#define CHW      (NLAT_IN * NLON_IN)   // 259200
#define BCTOT    128
#define G        4
#define NBCG     (BCTOT / G)           // 32
#define MAXR     2
#define PH       10
#define NTHREADS 256
#define SLOTS    400                   // 360 + 40 wrap mirror (max reach qA+35)
#define MIRROR   (SLOTS - NLON_OUT)    // 40
#define ROWB     (SLOTS * 16)          // 6400 B per row-parity plane

typedef float v2f __attribute__((ext_vector_type(2)));

__device__ __forceinline__ void PKF(v2f& a, v2f x, v2f c) {
    asm("v_pk_fma_f32 %0, %1, %2, %0" : "+v"(a) : "v"(x), "v"(c));
}

// ---------------- prep ----------------

__global__ void prep1_kernel(const int* __restrict__ seg, const int* __restrict__ lat,
                             const float* __restrict__ val, int nnz,
                             int* __restrict__ ptrh, int* __restrict__ hbase,
                             int* __restrict__ hlast, int* __restrict__ flags) {
    int idx = blockIdx.x * blockDim.x + threadIdx.x;
    if (idx >= NSEG * PH) return;
    int s = idx / PH, j = idx - s * PH;
    int lo = 0, hi = nnz;
    while (lo < hi) { int m = (lo + hi) >> 1; if (seg[m] < s) lo = m + 1; else hi = m; }
    int e0 = lo;
    lo = e0; hi = nnz;
    while (lo < hi) { int m = (lo + hi) >> 1; if (seg[m] < s + 1) lo = m + 1; else hi = m; }
    int e1 = lo;
    if (e0 >= e1) {
        ptrh[idx] = e0; flags[idx] = 0;
        if (j == 0) { hbase[s] = 1 << 28; hlast[s] = -(1 << 28); }
        return;
    }
    int hb = lat[e0];
    if (j == 0) { hbase[s] = hb; hlast[s] = lat[e1 - 1]; }
    int a;
    { int tg = hb + j; lo = e0; hi = e1;
      while (lo < hi) { int m = (lo + hi) >> 1; if (lat[m] < tg) lo = m + 1; else hi = m; }
      a = lo; }
    ptrh[idx] = a;
    int f = 0;
    if (j < PH - 1) {
        int tg = hb + j + 1; lo = a; hi = e1;
        while (lo < hi) { int m = (lo + hi) >> 1; if (lat[m] < tg) lo = m + 1; else hi = m; }
        int b = lo;
        if (b - a == NLON_IN) {
            float v0 = val[a], v1 = val[a + 240], v2 = val[a + 480];
            float d = fmaxf(fabsf(v0 - v1), fmaxf(fabsf(v0 - v2), fabsf(v1 - v2)));
            f = (d < 1e-5f) ? 1 : 0;
        }
    }
    flags[idx] = f;
}

__global__ void cf_kernel(const int* __restrict__ lat, const float* __restrict__ val,
                          const float* __restrict__ qw, int nnz, float* __restrict__ cfb) {
    int e = blockIdx.x * blockDim.x + threadIdx.x;
    if (e < nnz) cfb[e] = val[e] * qw[lat[e]];
}

// wave-parallel run builder: one wave per (s,j) row; 64-entry chunks.
__global__ void runs_kernel(const int* __restrict__ lon, const int* __restrict__ ptrh,
                            const int* __restrict__ flags,
                            int* __restrict__ runcnt, uint2* __restrict__ runslab) {
    const int idx  = blockIdx.x * 4 + (threadIdx.x >> 6);
    if (idx >= NSEG * PH) return;
    const int lane = threadIdx.x & 63;
    const int j = idx % PH;
    int runbase = 0;
    if (j < PH - 1) {
        const int a = ptrh[idx], b = ptrh[idx + 1];
        if (b > a && !flags[idx]) {
            for (int c = a; c < b; c += 64) {
                const int e = c + lane;
                const bool active = e < b;
                const int w   = active ? lon[e] : 0;
                const int wm1 = (active && e > a) ? lon[e - 1] : -99;
                const bool isStart = active && (lane == 0 || w != wm1 + 1);
                const unsigned long long mask = __ballot(isStart);
                if (isStart) {
                    const int cnt = min(64, b - c);
                    unsigned long long hv = (mask >> lane) >> 1;
                    const int len = hv ? __ffsll((long long)hv) : (cnt - lane);
                    const int cidx = __popcll(mask & ((1ull << lane) - 1ull));
                    const int s0 = ((w >> 1) + NLON_OUT - 1) % NLON_OUT;
                    runslab[a + runbase + cidx] = make_uint2(
                        (unsigned)e, (unsigned)(s0 | ((w & 1) << 9) | (len << 11)));
                }
                runbase += __popcll(mask);
            }
        }
    }
    if (lane == 0) runcnt[idx] = runbase;
}

// ---------------- main ----------------

__global__ __launch_bounds__(NTHREADS) void disco_kernel(
    const float* __restrict__ x,
    const float* __restrict__ cfb,
    const uint2* __restrict__ runslab,
    const int*   __restrict__ runcnt,
    const int*   __restrict__ ptrh,
    const int*   __restrict__ hbase,
    const int*   __restrict__ hlast,
    const int*   __restrict__ flags,
    float*       __restrict__ out)
{
    __shared__ float4 ldsx[MAXR * 2][SLOTS];   // 25,600 B
    v2f (*accbuf)[6] = (v2f(*)[6])&ldsx[0][0]; // epilogue overlay (after barrier)

    const int tid      = threadIdx.x;
    const int lane     = tid & 63;
    const int wpair    = tid >> 7;             // 0: waves 0-1, 1: waves 2-3
    const int pairlane = tid & 127;
    const int pid      = (pairlane < 120) ? pairlane : pairlane - 120;
    const int p0       = 3 * pid;
    const int bc0      = blockIdx.x * G;
    const int ty       = blockIdx.y;
    const int t        = (ty & 1) ? (NLAT_OUT - 1 - (ty >> 1)) : (ty >> 1); // poles first
    const int s        = blockIdx.z * NLAT_OUT + t;
    const int hb = hbase[s], hl = hlast[s];    // empty: hb > hl

    v2f a0l = {0.f, 0.f}, a0h = a0l, a1l = a0l, a1h = a0l, a2l = a0l, a2h = a0l;
    const char* lb = (const char*)&ldsx[0][0];

    float2 sv0[4], sv1[4], sv2[4];             // T14 staging registers
    const float* xb = x + (size_t)bc0 * CHW;

#define LOADW(R0)                                                              \
    {                                                                          \
        {   const int idx_ = tid;                                              \
            const int rr_ = idx_ >= 360;                                       \
            const int m_  = idx_ - 360 * rr_;                                  \
            const int row_ = min((R0) + rr_, hl);                              \
            const float* xr_ = xb + (size_t)row_ * NLON_IN + 2 * m_;           \
            sv0[0] = *(const float2*)(xr_);                                    \
            sv0[1] = *(const float2*)(xr_ + CHW);                              \
            sv0[2] = *(const float2*)(xr_ + 2 * CHW);                          \
            sv0[3] = *(const float2*)(xr_ + 3 * CHW);                          \
        }                                                                      \
        {   const int idx_ = tid + 256;                                        \
            const int rr_ = idx_ >= 360;                                       \
            const int m_  = idx_ - 360 * rr_;                                  \
            const int row_ = min((R0) + rr_, hl);                              \
            const float* xr_ = xb + (size_t)row_ * NLON_IN + 2 * m_;           \
            sv1[0] = *(const float2*)(xr_);                                    \
            sv1[1] = *(const float2*)(xr_ + CHW);                              \
            sv1[2] = *(const float2*)(xr_ + 2 * CHW);                          \
            sv1[3] = *(const float2*)(xr_ + 3 * CHW);                          \
        }                                                                      \
        if (tid < 208) {                                                       \
            const int m_  = tid + 512 - 360;                                   \
            const int row_ = min((R0) + 1, hl);                                \
            const float* xr_ = xb + (size_t)row_ * NLON_IN + 2 * m_;           \
            sv2[0] = *(const float2*)(xr_);                                    \
            sv2[1] = *(const float2*)(xr_ + CHW);                              \
            sv2[2] = *(const float2*)(xr_ + 2 * CHW);                          \
            sv2[3] = *(const float2*)(xr_ + 3 * CHW);                          \
        }                                                                      \
    }

#define WRITEW()                                                               \
    {                                                                          \
        {   const int idx_ = tid;                                              \
            const int rr_ = idx_ >= 360;                                       \
            const int m_  = idx_ - 360 * rr_;                                  \
            const float4 ev_ = {sv0[0].x, sv0[1].x, sv0[2].x, sv0[3].x};       \
            const float4 ov_ = {sv0[0].y, sv0[1].y, sv0[2].y, sv0[3].y};       \
            ldsx[2 * rr_ + 0][m_] = ev_;                                       \
            ldsx[2 * rr_ + 1][m_] = ov_;                                       \
            if (m_ < MIRROR) {                                                 \
                ldsx[2 * rr_ + 0][NLON_OUT + m_] = ev_;                        \
                ldsx[2 * rr_ + 1][NLON_OUT + m_] = ov_;                        \
            }                                                                  \
        }                                                                      \
        {   const int idx_ = tid + 256;                                        \
            const int rr_ = idx_ >= 360;                                       \
            const int m_  = idx_ - 360 * rr_;                                  \
            const float4 ev_ = {sv1[0].x, sv1[1].x, sv1[2].x, sv1[3].x};       \
            const float4 ov_ = {sv1[0].y, sv1[1].y, sv1[2].y, sv1[3].y};       \
            ldsx[2 * rr_ + 0][m_] = ev_;                                       \
            ldsx[2 * rr_ + 1][m_] = ov_;                                       \
            if (m_ < MIRROR) {                                                 \
                ldsx[2 * rr_ + 0][NLON_OUT + m_] = ev_;                        \
                ldsx[2 * rr_ + 1][NLON_OUT + m_] = ov_;                        \
            }                                                                  \
        }                                                                      \
        if (tid < 208) {                                                       \
            const int m_ = tid + 512 - 360;                                    \
            const float4 ev_ = {sv2[0].x, sv2[1].x, sv2[2].x, sv2[3].x};       \
            const float4 ov_ = {sv2[0].y, sv2[1].y, sv2[2].y, sv2[3].y};       \
            ldsx[2][m_] = ev_;                                                 \
            ldsx[3][m_] = ov_;                                                 \
            if (m_ < MIRROR) {                                                 \
                ldsx[2][NLON_OUT + m_] = ev_;                                  \
                ldsx[3][NLON_OUT + m_] = ov_;                                  \
            }                                                                  \
        }                                                                      \
    }

    if (hb <= hl) {
        LOADW(hb);                              // prologue: first window in flight
        for (int r0 = hb; r0 <= hl; r0 += MAXR) {
            const int rn = min(MAXR, hl - r0 + 1);
            __syncthreads();                    // readers of previous window done
            WRITEW();                           // vmcnt wait hidden under prev compute
            if (r0 + MAXR <= hl) LOADW(r0 + MAXR);
            __syncthreads();                    // LDS ready
            // ---- compute window ----
            for (int r = 0; r < rn; ++r) {
                const int j = (r0 + r) - hb;
                if (j < 0 || j >= PH - 1) continue;
                if ((j & 1) != wpair) continue;  // wave-uniform
                const int idx = s * PH + j;
                const int a = ptrh[idx], b = ptrh[idx + 1];
                if (a >= b) continue;
                const int rp0 = (j & 1) * 2;
                if (flags[idx]) {                // constant-val full row: cf*rowsum
                    float4 v = {0.f, 0.f, 0.f, 0.f};
                    for (int m = lane; m < NLON_OUT; m += 64) {
                        const float4 u0 = ldsx[rp0][m], u1 = ldsx[rp0 + 1][m];
                        v.x += u0.x + u1.x; v.y += u0.y + u1.y;
                        v.z += u0.z + u1.z; v.w += u0.w + u1.w;
                    }
#pragma unroll
                    for (int o = 32; o >= 1; o >>= 1) {
                        v.x += __shfl_xor(v.x, o); v.y += __shfl_xor(v.y, o);
                        v.z += __shfl_xor(v.z, o); v.w += __shfl_xor(v.w, o);
                    }
                    const float cf = cfb[a];
                    a0l.x = fmaf(cf, v.x, a0l.x); a0l.y = fmaf(cf, v.y, a0l.y);
                    a0h.x = fmaf(cf, v.z, a0h.x); a0h.y = fmaf(cf, v.w, a0h.y);
                    a1l.x = fmaf(cf, v.x, a1l.x); a1l.y = fmaf(cf, v.y, a1l.y);
                    a1h.x = fmaf(cf, v.z, a1h.x); a1h.y = fmaf(cf, v.w, a1h.y);
                    a2l.x = fmaf(cf, v.x, a2l.x); a2l.y = fmaf(cf, v.y, a2l.y);
                    a2h.x = fmaf(cf, v.z, a2h.x); a2h.y = fmaf(cf, v.w, a2h.y);
                    continue;
                }
                const int rc = runcnt[idx];      // >= 1 here (b>a, not flagged)
                uint2 Rcur = runslab[a];         // first header, issued early
                for (int rr = 0; rr < rc; ++rr) {
                    const uint2 Rnext = runslab[a + min(rr + 1, rc - 1)];
                    const int e0  = __builtin_amdgcn_readfirstlane((int)Rcur.x);
                    const int y   = __builtin_amdgcn_readfirstlane((int)Rcur.y);
                    const int s0A = y & 511;
                    const int odd = (y >> 9) & 1;
                    const int len = y >> 11;
                    int qA = s0A - p0 - 2; qA += (qA >> 31) & NLON_OUT;
                    const char* baseA = lb + (size_t)(rp0 + odd) * ROWB + ((size_t)qA << 4);
                    const char* baseB = lb + (size_t)(rp0 + (odd ^ 1)) * ROWB
                                           + ((size_t)(qA + odd) << 4);
                    const float* cfp = cfb + e0;
                    int i = 0;
                    if (len >= 8) {
                        v2f A0l = *(const v2f*)(baseA +  0), A0h = *(const v2f*)(baseA +  8);
                        v2f A1l = *(const v2f*)(baseA + 16), A1h = *(const v2f*)(baseA + 24);
                        v2f A2l = *(const v2f*)(baseA + 32), A2h = *(const v2f*)(baseA + 40);
                        v2f B0l = *(const v2f*)(baseB +  0), B0h = *(const v2f*)(baseB +  8);
                        v2f B1l = *(const v2f*)(baseB + 16), B1h = *(const v2f*)(baseB + 24);
                        v2f B2l = *(const v2f*)(baseB + 32), B2h = *(const v2f*)(baseB + 40);
                        v2f A3l, A3h, B3l, B3h;
                        const char* ldA = baseA + 48;
                        const char* ldB = baseB + 48;
                        for (; i + 8 <= len; i += 8) {
                            float cs; v2f c;
                            A3l = *(const v2f*)(ldA); A3h = *(const v2f*)(ldA + 8); ldA += 16;
                            cs = cfp[i + 0]; c = (v2f){cs, cs};
                            PKF(a2l, A0l, c); PKF(a2h, A0h, c);
                            PKF(a1l, A1l, c); PKF(a1h, A1h, c);
                            PKF(a0l, A2l, c); PKF(a0h, A2h, c);
                            B3l = *(const v2f*)(ldB); B3h = *(const v2f*)(ldB + 8); ldB += 16;
                            cs = cfp[i + 1]; c = (v2f){cs, cs};
                            PKF(a2l, B0l, c); PKF(a2h, B0h, c);
                            PKF(a1l, B1l, c); PKF(a1h, B1h, c);
                            PKF(a0l, B2l, c); PKF(a0h, B2h, c);
                            A0l = *(const v2f*)(ldA); A0h = *(const v2f*)(ldA + 8); ldA += 16;
                            cs = cfp[i + 2]; c = (v2f){cs, cs};
                            PKF(a2l, A1l, c); PKF(a2h, A1h, c);
                            PKF(a1l, A2l, c); PKF(a1h, A2h, c);
                            PKF(a0l, A3l, c); PKF(a0h, A3h, c);
                            B0l = *(const v2f*)(ldB); B0h = *(const v2f*)(ldB + 8); ldB += 16;
                            cs = cfp[i + 3]; c = (v2f){cs, cs};
                            PKF(a2l, B1l, c); PKF(a2h, B1h, c);
                            PKF(a1l, B2l, c); PKF(a1h, B2h, c);
                            PKF(a0l, B3l, c); PKF(a0h, B3h, c);
                            A1l = *(const v2f*)(ldA); A1h = *(const v2f*)(ldA + 8); ldA += 16;
                            cs = cfp[i + 4]; c = (v2f){cs, cs};
                            PKF(a2l, A2l, c); PKF(a2h, A2h, c);
                            PKF(a1l, A3l, c); PKF(a1h, A3h, c);
                            PKF(a0l, A0l, c); PKF(a0h, A0h, c);
                            B1l = *(const v2f*)(ldB); B1h = *(const v2f*)(ldB + 8); ldB += 16;
                            cs = cfp[i + 5]; c = (v2f){cs, cs};
                            PKF(a2l, B2l, c); PKF(a2h, B2h, c);
                            PKF(a1l, B3l, c); PKF(a1h, B3h, c);
                            PKF(a0l, B0l, c); PKF(a0h, B0h, c);
                            A2l = *(const v2f*)(ldA); A2h = *(const v2f*)(ldA + 8); ldA += 16;
                            cs = cfp[i + 6]; c = (v2f){cs, cs};
                            PKF(a2l, A3l, c); PKF(a2h, A3h, c);
                            PKF(a1l, A0l, c); PKF(a1h, A0h, c);
                            PKF(a0l, A1l, c); PKF(a0h, A1h, c);
                            B2l = *(const v2f*)(ldB); B2h = *(const v2f*)(ldB + 8); ldB += 16;
                            cs = cfp[i + 7]; c = (v2f){cs, cs};
                            PKF(a2l, B3l, c); PKF(a2h, B3h, c);
                            PKF(a1l, B0l, c); PKF(a1h, B0h, c);
                            PKF(a0l, B1l, c); PKF(a0h, B1h, c);
                        }
                    }
                    for (; i < len; ++i) {       // tail / short runs
                        const int m = i >> 1;
                        const char* bp = (i & 1) ? (baseB + ((size_t)m << 4))
                                                 : (baseA + ((size_t)m << 4));
                        const float cs = cfp[i]; const v2f c = (v2f){cs, cs};
                        const v2f w0l = *(const v2f*)(bp +  0), w0h = *(const v2f*)(bp +  8);
                        const v2f w1l = *(const v2f*)(bp + 16), w1h = *(const v2f*)(bp + 24);
                        const v2f w2l = *(const v2f*)(bp + 32), w2h = *(const v2f*)(bp + 40);
                        PKF(a2l, w0l, c); PKF(a2h, w0h, c);
                        PKF(a1l, w1l, c); PKF(a1h, w1h, c);
                        PKF(a0l, w2l, c); PKF(a0h, w2h, c);
                    }
                    Rcur = Rnext;
                }
            }
        }
    }

    // ---- combine pair-1 into pair-0, store (accbuf overlays ldsx) ----
    __syncthreads();
    if (wpair == 1 && pairlane < 120) {
        accbuf[pid][0] = a0l; accbuf[pid][1] = a0h;
        accbuf[pid][2] = a1l; accbuf[pid][3] = a1h;
        accbuf[pid][4] = a2l; accbuf[pid][5] = a2h;
    }
    __syncthreads();
    if (wpair == 0 && pairlane < 120) {
        a0l += accbuf[pid][0]; a0h += accbuf[pid][1];
        a1l += accbuf[pid][2]; a1h += accbuf[pid][3];
        a2l += accbuf[pid][4]; a2h += accbuf[pid][5];
        const size_t cs_ = (size_t)NSEG * NLON_OUT;
        const size_t ob  = ((size_t)bc0 * NSEG + s) * NLON_OUT + p0;
        out[ob]              = a0l.x; out[ob + 1]              = a1l.x; out[ob + 2]              = a2l.x;
        out[ob + cs_]        = a0l.y; out[ob + cs_ + 1]        = a1l.y; out[ob + cs_ + 2]        = a2l.y;
        out[ob + 2 * cs_]    = a0h.x; out[ob + 2 * cs_ + 1]    = a1h.x; out[ob + 2 * cs_ + 2]    = a2h.x;
        out[ob + 3 * cs_]    = a0h.y; out[ob + 3 * cs_ + 1]    = a1h.y; out[ob + 3 * cs_ + 2]    = a2h.y;
    }
#undef LOADW
#undef WRITEW
}

// ---------------- fallback (tiny ws) ----------------

__global__ void segptr_kernel(const int* __restrict__ seg, int nnz, int* __restrict__ ptr) {
    int s = blockIdx.x * blockDim.x + threadIdx.x;
    if (s > NSEG) return;
    if (s == NSEG) { ptr[NSEG] = nnz; return; }
    int lo = 0, hi = nnz;
    while (lo < hi) { int m = (lo + hi) >> 1; if (seg[m] < s) lo = m + 1; else hi = m; }
    ptr[s] = lo;
}

__global__ __launch_bounds__(384) void disco_simple_kernel(
    const float* __restrict__ x, const float* __restrict__ qw,
    const int* __restrict__ lat, const int* __restrict__ lon,
    const float* __restrict__ val, const int* __restrict__ ptr,
    float* __restrict__ out)
{
    const int p = threadIdx.x;
    if (p >= NLON_OUT) return;
    const int kt = blockIdx.x, bc0 = blockIdx.y * 8;
    const int e0 = ptr[kt], e1 = ptr[kt + 1];
    float acc[8];
#pragma unroll
    for (int g = 0; g < 8; ++g) acc[g] = 0.0f;
    const int pw = 2 * p + 2;
    const float* xb = x + (size_t)bc0 * CHW;
    for (int e = e0; e < e1; ++e) {
        const int h = lat[e], w = lon[e];
        const float cf = val[e] * qw[h];
        int col = w - pw; if (col < 0) col += NLON_IN;
        const float* src = xb + h * NLON_IN + col;
#pragma unroll
        for (int g = 0; g < 8; ++g) acc[g] = fmaf(cf, src[(size_t)g * CHW], acc[g]);
    }
    const size_t ob = ((size_t)bc0 * NSEG + kt) * NLON_OUT + p;
#pragma unroll
    for (int g = 0; g < 8; ++g) out[ob + (size_t)g * NSEG * NLON_OUT] = acc[g];
}

// ---------------- launcher ----------------

extern "C" void kernel_launch(void* const* d_in, const int* in_sizes, int n_in,
                              void* d_out, int out_size, void* d_ws, size_t ws_size,
                              hipStream_t stream)
{
    const float* x   = (const float*)d_in[0];   // [2,64,360,720] f32
    const float* qw  = (const float*)d_in[1];   // [360,1] f32
    const int*   seg = (const int*)  d_in[2];   // [nnz] i32 sorted asc
    const int*   lat = (const int*)  d_in[3];
    const int*   lon = (const int*)  d_in[4];
    const float* val = (const float*)d_in[5];
    const int    nnz = in_sizes[2];
    const int    nnzpad = (nnz + 3) & ~3;

    char* w = (char*)d_ws;
    size_t off = 0;
    int* ptrh   = (int*)(w + off); off += (size_t)NSEG * PH * 4;   // 21600
    int* hbase  = (int*)(w + off); off += NSEG * 4;
    int* hlast  = (int*)(w + off); off += NSEG * 4;
    int* flags  = (int*)(w + off); off += (size_t)NSEG * PH * 4;
    int* runcnt = (int*)(w + off); off += (size_t)NSEG * PH * 4;
    float* cfb  = (float*)(w + off); off += (size_t)nnzpad * 4;
    off = (off + 7) & ~(size_t)7;
    uint2* runslab = (uint2*)(w + off); off += (size_t)nnz * 8;

    if (ws_size < off) {                         // tiny ws: slow-but-correct path
        int* ptr = (int*)d_ws;
        segptr_kernel<<<(NSEG + 1 + 255) / 256, 256, 0, stream>>>(seg, nnz, ptr);
        dim3 grid(NSEG, BCTOT / 8);
        disco_simple_kernel<<<grid, 384, 0, stream>>>(x, qw, lat, lon, val, ptr,
                                                      (float*)d_out);
        return;
    }

    prep1_kernel<<<(NSEG * PH + 255) / 256, 256, 0, stream>>>(seg, lat, val, nnz,
                                                              ptrh, hbase, hlast, flags);
    cf_kernel<<<(nnz + 255) / 256, 256, 0, stream>>>(lat, val, qw, nnz, cfb);
    runs_kernel<<<(NSEG * PH + 3) / 4, 256, 0, stream>>>(lon, ptrh, flags,
                                                         runcnt, runslab);

    dim3 grid(NBCG, NLAT_OUT, KSIZE);
    disco_kernel<<<grid, NTHREADS, 0, stream>>>(x, cfb, runslab, runcnt,
                                                ptrh, hbase, hlast, flags,
                                                (float*)d_out);
}